// Round 1
// baseline (205.127 us; speedup 1.0000x reference)
//
#include <hip/hip_runtime.h>

#define B_ 32
#define N_ 4096
#define D_ 64
#define C_ 129
#define BC_ 4
#define CG_ 33   // ceil(C_/4): 4 waves/block = 4 clusters/block
#define QROWS_ 17  // q-rows per attn block: 8 blocks/b, exactly 256 blocks total

// ---------------------------------------------------------------- counting sort
// One block per cluster-batch row, 1024 threads (4x the old parallelism on the
// only 4 CUs this kernel can occupy). Produces counts (float), offsets [C_+1],
// and sidx: row indices sorted by cluster (order within cluster arbitrary).
__global__ __launch_bounds__(1024) void k_sort(const int* __restrict__ cl,
                                               float* __restrict__ counts,
                                               int* __restrict__ offsets,
                                               int* __restrict__ sidx) {
    __shared__ int cnt[C_];
    __shared__ int base[C_];
    __shared__ int cur[C_];
    int bc = blockIdx.x, tid = threadIdx.x;
    for (int i = tid; i < C_; i += 1024) { cnt[i] = 0; cur[i] = 0; }
    __syncthreads();
    const int4* g4 = (const int4*)(cl + bc * N_);
    // histogram, int4 reads (N/4 = 1024 int4s, exactly 1 per thread)
    for (int n = tid; n < N_ / 4; n += 1024) {
        int4 c4 = g4[n];
        atomicAdd(&cnt[c4.x], 1);
        atomicAdd(&cnt[c4.y], 1);
        atomicAdd(&cnt[c4.z], 1);
        atomicAdd(&cnt[c4.w], 1);
    }
    __syncthreads();
    // parallel exclusive prefix: thread t sums cnt[0..t) (C is tiny)
    if (tid < C_) {
        int acc = 0;
        for (int i = 0; i < tid; i++) acc += cnt[i];
        base[tid] = acc;
    }
    __syncthreads();
    for (int i = tid; i < C_; i += 1024) {
        counts[bc * C_ + i] = (float)cnt[i];
        offsets[bc * (C_ + 1) + i] = base[i];
    }
    if (tid == 0) offsets[bc * (C_ + 1) + C_] = N_;
    // scatter, int4 reads
    for (int n = tid; n < N_ / 4; n += 1024) {
        int4 c4 = g4[n];
        int n0 = n * 4;
        sidx[bc * N_ + base[c4.x] + atomicAdd(&cur[c4.x], 1)] = n0;
        sidx[bc * N_ + base[c4.y] + atomicAdd(&cur[c4.y], 1)] = n0 + 1;
        sidx[bc * N_ + base[c4.z] + atomicAdd(&cur[c4.z], 1)] = n0 + 2;
        sidx[bc * N_ + base[c4.w] + atomicAdd(&cur[c4.w], 1)] = n0 + 3;
    }
}

// ---------------------------------------------------------------- fused segment sums
// One wave per (b, cluster); Q, K, V together: 12 independent 1KB row-gathers
// in flight per iteration (lane = sub*16 + d4). Index loads for iteration i+1
// are issued BEFORE iteration i's data is consumed (software pipeline), so the
// si -> address dependency hides under the outstanding data loads.
// Centers written once, pre-scaled by 1/count. No atomics.
__global__ __launch_bounds__(256) void k_segsum4(const float* __restrict__ q,
                                                 const float* __restrict__ k,
                                                 const float* __restrict__ v,
                                                 const int* __restrict__ offsets,
                                                 const int* __restrict__ sidx,
                                                 float* __restrict__ sums) {
    int bid = blockIdx.x;
    int cg = bid % CG_;
    int b = bid / CG_;
    int wave = threadIdx.x >> 6, lane = threadIdx.x & 63;
    int c = cg * 4 + wave;
    if (c >= C_) return;
    int bc = b & 3;
    int start = offsets[bc * (C_ + 1) + c];
    int end = offsets[bc * (C_ + 1) + c + 1];
    int cnt = end - start;
    int sub = lane >> 4, d4 = lane & 15;

    const float4* q4 = (const float4*)(q + (size_t)b * N_ * D_);
    const float4* k4 = (const float4*)(k + (size_t)b * N_ * D_);
    const float4* v4 = (const float4*)(v + (size_t)b * N_ * D_);
    const int* si = sidx + bc * N_;

    float4 aq = make_float4(0.f, 0.f, 0.f, 0.f);
    float4 ak = make_float4(0.f, 0.f, 0.f, 0.f);
    float4 av = make_float4(0.f, 0.f, 0.f, 0.f);

    if (cnt > 0) {
        int last = end - 1;
        // prologue: indices for iteration 0
        int ia = start + sub, ib = ia + 4, ic = ia + 8, id = ia + 12;
        int ra = si[min(ia, last)], rb = si[min(ib, last)];
        int rc = si[min(ic, last)], rd = si[min(id, last)];
        for (int i0 = start; i0 < end; i0 += 16) {
            int ca = ia, cb = ib, cc = ic, cd = id;
            int ua = ra, ub = rb, uc = rc, ud = rd;
            // prefetch next iteration's indices (independent of data below)
            ia += 16; ib += 16; ic += 16; id += 16;
            if (i0 + 16 < end) {
                ra = si[min(ia, last)]; rb = si[min(ib, last)];
                rc = si[min(ic, last)]; rd = si[min(id, last)];
            }
            float ma = (ca < end) ? 1.f : 0.f;
            float mb = (cb < end) ? 1.f : 0.f;
            float mc = (cc < end) ? 1.f : 0.f;
            float md = (cd < end) ? 1.f : 0.f;
            float4 qa = q4[ua * 16 + d4], qb = q4[ub * 16 + d4];
            float4 qc = q4[uc * 16 + d4], qd = q4[ud * 16 + d4];
            float4 ka = k4[ua * 16 + d4], kb = k4[ub * 16 + d4];
            float4 kc = k4[uc * 16 + d4], kd = k4[ud * 16 + d4];
            float4 va = v4[ua * 16 + d4], vb = v4[ub * 16 + d4];
            float4 vc = v4[uc * 16 + d4], vd = v4[ud * 16 + d4];
            aq.x += ma * qa.x + mb * qb.x + mc * qc.x + md * qd.x;
            aq.y += ma * qa.y + mb * qb.y + mc * qc.y + md * qd.y;
            aq.z += ma * qa.z + mb * qb.z + mc * qc.z + md * qd.z;
            aq.w += ma * qa.w + mb * qb.w + mc * qc.w + md * qd.w;
            ak.x += ma * ka.x + mb * kb.x + mc * kc.x + md * kd.x;
            ak.y += ma * ka.y + mb * kb.y + mc * kc.y + md * kd.y;
            ak.z += ma * ka.z + mb * kb.z + mc * kc.z + md * kd.z;
            ak.w += ma * ka.w + mb * kb.w + mc * kc.w + md * kd.w;
            av.x += ma * va.x + mb * vb.x + mc * vc.x + md * vd.x;
            av.y += ma * va.y + mb * vb.y + mc * vc.y + md * vd.y;
            av.z += ma * va.z + mb * vb.z + mc * vc.z + md * vd.z;
            av.w += ma * va.w + mb * vb.w + mc * vc.w + md * vd.w;
        }
    }
#pragma unroll
    for (int off = 16; off <= 32; off <<= 1) {
        aq.x += __shfl_xor(aq.x, off, 64); aq.y += __shfl_xor(aq.y, off, 64);
        aq.z += __shfl_xor(aq.z, off, 64); aq.w += __shfl_xor(aq.w, off, 64);
        ak.x += __shfl_xor(ak.x, off, 64); ak.y += __shfl_xor(ak.y, off, 64);
        ak.z += __shfl_xor(ak.z, off, 64); ak.w += __shfl_xor(ak.w, off, 64);
        av.x += __shfl_xor(av.x, off, 64); av.y += __shfl_xor(av.y, off, 64);
        av.z += __shfl_xor(av.z, off, 64); av.w += __shfl_xor(av.w, off, 64);
    }
    if (sub == 0) {
        float w = (cnt > 0) ? 1.f / (float)cnt : 0.f;
        float4 oq = make_float4(aq.x * w, aq.y * w, aq.z * w, aq.w * w);
        float4 ok = make_float4(ak.x * w, ak.y * w, ak.z * w, ak.w * w);
        float4 ov = make_float4(av.x * w, av.y * w, av.z * w, av.w * w);
        ((float4*)(sums + (size_t)b * C_ * D_))[c * 16 + d4] = oq;
        ((float4*)(sums + ((size_t)B_ + b) * C_ * D_))[c * 16 + d4] = ok;
        ((float4*)(sums + ((size_t)2 * B_ + b) * C_ * D_))[c * 16 + d4] = ov;
    }
}

// ---------------------------------------------------------------- attention over centers
// grid: B * 8 blocks (17 q-rows per block -> exactly 256 blocks, one scheduling
// round). V centers are NOT staged in LDS: sums is 3.2 MB (L2/L3-resident) and
// the PV access is a 256B broadcast row per instruction. LDS drops 83KB -> 48KB
// -> 3 blocks/CU (12 waves) for real latency hiding.
__global__ __launch_bounds__(256) void k_attn(const float* __restrict__ sums,
                                              const float* __restrict__ counts,
                                              float* __restrict__ vout,
                                              float* __restrict__ aout) {
    __shared__ float4 kc4[C_ * 17];       // K centers, 16 data float4 + 1 pad
    __shared__ float4 qr4[QROWS_ * 16];   // this block's Q rows
    __shared__ float cnt_s[C_];
    __shared__ float arow[4][4][132];     // per-wave A rows (k=0..128, pad to 132)

    int b = blockIdx.x >> 3;
    int qg = blockIdx.x & 7;
    int q0 = qg * QROWS_;
    int qcnt = min(QROWS_, C_ - q0);
    int tid = threadIdx.x;

    for (int i = tid; i < C_; i += 256)
        cnt_s[i] = counts[(b & 3) * C_ + i];
    __syncthreads();

    const float4* qsum4 = (const float4*)(sums + (size_t)b * C_ * D_);
    const float4* ksum4 = (const float4*)(sums + ((size_t)B_ + b) * C_ * D_);
    const float4* vsum4 = (const float4*)(sums + ((size_t)2 * B_ + b) * C_ * D_);

    for (int i = tid; i < C_ * 16; i += 256) {
        int c = i >> 4, d4 = i & 15;
        kc4[c * 17 + d4] = ksum4[i];
    }
    for (int i = tid; i < qcnt * 16; i += 256) {
        int r = i >> 4, d4 = i & 15;
        qr4[i] = qsum4[(q0 + r) * 16 + d4];
    }
    __syncthreads();

    int wave = tid >> 6, lane = tid & 63;

    for (int tt = wave; tt * 4 < qcnt; tt += 4) {
        int t4 = tt * 4;
        // ---- QK: 4 q-rows x (k=lane, k=lane+64, k=128)
        float s0[4] = {0, 0, 0, 0}, s1[4] = {0, 0, 0, 0}, s2[4] = {0, 0, 0, 0};
        for (int d4 = 0; d4 < 16; d4++) {
            float4 kv0 = kc4[lane * 17 + d4];
            float4 kv1 = kc4[(lane + 64) * 17 + d4];
            float4 kv2 = kc4[128 * 17 + d4];
#pragma unroll
            for (int r = 0; r < 4; r++) {
                int rr = t4 + r; if (rr >= qcnt) rr = qcnt - 1;
                float4 qv = qr4[rr * 16 + d4];
                s0[r] += qv.x * kv0.x + qv.y * kv0.y + qv.z * kv0.z + qv.w * kv0.w;
                s1[r] += qv.x * kv1.x + qv.y * kv1.y + qv.z * kv1.z + qv.w * kv1.w;
                s2[r] += qv.x * kv2.x + qv.y * kv2.y + qv.z * kv2.z + qv.w * kv2.w;
            }
        }
        // ---- softmax (weighted by counts, renormalized)
#pragma unroll
        for (int r = 0; r < 4; r++) {
            if (t4 + r >= qcnt) break;
            int qrow = q0 + t4 + r;
            float m = fmaxf(s0[r], s1[r]);
            if (lane == 0) m = fmaxf(m, s2[r]);
            for (int off = 32; off > 0; off >>= 1)
                m = fmaxf(m, __shfl_xor(m, off, 64));
            float e0 = __expf(s0[r] - m) * cnt_s[lane];
            float e1 = __expf(s1[r] - m) * cnt_s[lane + 64];
            float e2 = (lane == 0) ? __expf(s2[r] - m) * cnt_s[128] : 0.f;
            float sum = e0 + e1 + e2;
            for (int off = 32; off > 0; off >>= 1)
                sum += __shfl_xor(sum, off, 64);
            float inv = 1.f / sum;
            float a0 = e0 * inv, a1 = e1 * inv;
            arow[wave][r][lane] = a0;
            arow[wave][r][64 + lane] = a1;
            if (lane == 0) {
                arow[wave][r][128] = e2 * inv;
                aout[b * C_ + qrow] = a0;   // A_full[:, :, 0]
            }
        }
        __builtin_amdgcn_s_waitcnt(0);  // ensure arow writes visible in-wave
        // ---- V product: lane = (row within tile, d4); V from global (L2-hit)
        int rr = lane >> 4, d4 = lane & 15;
        const float4* ar4 = (const float4*)arow[wave][rr];
        float4 o = make_float4(0.f, 0.f, 0.f, 0.f);
        for (int k4 = 0; k4 < 32; k4++) {
            float4 a4 = ar4[k4];
            float4 v0 = vsum4[(k4 * 4 + 0) * 16 + d4];
            float4 v1 = vsum4[(k4 * 4 + 1) * 16 + d4];
            float4 v2 = vsum4[(k4 * 4 + 2) * 16 + d4];
            float4 v3 = vsum4[(k4 * 4 + 3) * 16 + d4];
            o.x += a4.x * v0.x + a4.y * v1.x + a4.z * v2.x + a4.w * v3.x;
            o.y += a4.x * v0.y + a4.y * v1.y + a4.z * v2.y + a4.w * v3.y;
            o.z += a4.x * v0.z + a4.y * v1.z + a4.z * v2.z + a4.w * v3.z;
            o.w += a4.x * v0.w + a4.y * v1.w + a4.z * v2.w + a4.w * v3.w;
        }
        {
            float a128 = arow[wave][rr][128];
            float4 vv = vsum4[128 * 16 + d4];
            o.x += a128 * vv.x; o.y += a128 * vv.y;
            o.z += a128 * vv.z; o.w += a128 * vv.w;
        }
        if (t4 + rr < qcnt) {
            float4* dst = (float4*)(vout + ((size_t)b * C_ + (q0 + t4 + rr)) * D_);
            dst[d4] = o;
        }
    }
}

// ---------------------------------------------------------------- gather
__global__ __launch_bounds__(256) void k_gather(const float* __restrict__ vout,
                                                const int* __restrict__ cl,
                                                float* __restrict__ out) {
    int idx = blockIdx.x * 256 + threadIdx.x;   // over B*N*16 float4s
    int d4 = idx & 15;
    int n = (idx >> 4) & (N_ - 1);
    int b = idx >> 16;
    int c = cl[(b & 3) * N_ + n];
    const float4* src = (const float4*)(vout + ((size_t)b * C_ + c) * D_);
    ((float4*)out)[idx] = src[d4];
}

// ---------------------------------------------------------------- launch
extern "C" void kernel_launch(void* const* d_in, const int* in_sizes, int n_in,
                              void* d_out, int out_size, void* d_ws, size_t ws_size,
                              hipStream_t stream) {
    const float* q = (const float*)d_in[0];
    const float* k = (const float*)d_in[1];
    const float* v = (const float*)d_in[2];
    const int* cl = (const int*)d_in[3];
    float* out = (float*)d_out;
    float* aout = out + (size_t)B_ * N_ * D_;   // A_full[:, :, 0] tail

    float* ws = (float*)d_ws;
    float* counts = ws;                                   // [4][C_] (pad to 1024)
    float* sums = ws + 1024;                              // [3][B_][C_][D_] pre-scaled centers
    float* vout = sums + (size_t)3 * B_ * C_ * D_;        // [B_][C_][D_]
    int* offsets = (int*)(vout + (size_t)B_ * C_ * D_);   // [4][C_+1]
    int* sidx = offsets + 4 * (C_ + 1);                   // [4][N_]

    k_sort<<<BC_, 1024, 0, stream>>>(cl, counts, offsets, sidx);
    k_segsum4<<<B_ * CG_, 256, 0, stream>>>(q, k, v, offsets, sidx, sums);
    k_attn<<<B_ * 8, 256, 0, stream>>>(sums, counts, vout, aout);
    k_gather<<<(B_ * N_ * 16) / 256, 256, 0, stream>>>(vout, cl, out);
}

// Round 2
// 168.100 us; speedup vs baseline: 1.2203x; 1.2203x over previous
//
#include <hip/hip_runtime.h>

#define B_ 32
#define N_ 4096
#define D_ 64
#define C_ 129
#define BC_ 4
#define CG_ 33   // ceil(C_/4): 4 waves/block = 4 clusters/block
#define QROWS_ 17  // q-rows per attn block: 8 blocks/b, exactly 256 blocks total

// ---------------------------------------------------------------- counting sort
// One block per cluster-batch row, 1024 threads. Produces counts (float),
// offsets [C_+1], and sidx: row indices sorted by cluster.
__global__ __launch_bounds__(1024) void k_sort(const int* __restrict__ cl,
                                               float* __restrict__ counts,
                                               int* __restrict__ offsets,
                                               int* __restrict__ sidx) {
    __shared__ int cnt[C_];
    __shared__ int base[C_];
    __shared__ int cur[C_];
    int bc = blockIdx.x, tid = threadIdx.x;
    for (int i = tid; i < C_; i += 1024) { cnt[i] = 0; cur[i] = 0; }
    __syncthreads();
    const int4* g4 = (const int4*)(cl + bc * N_);
    for (int n = tid; n < N_ / 4; n += 1024) {
        int4 c4 = g4[n];
        atomicAdd(&cnt[c4.x], 1);
        atomicAdd(&cnt[c4.y], 1);
        atomicAdd(&cnt[c4.z], 1);
        atomicAdd(&cnt[c4.w], 1);
    }
    __syncthreads();
    if (tid < C_) {
        int acc = 0;
        for (int i = 0; i < tid; i++) acc += cnt[i];
        base[tid] = acc;
    }
    __syncthreads();
    for (int i = tid; i < C_; i += 1024) {
        counts[bc * C_ + i] = (float)cnt[i];
        offsets[bc * (C_ + 1) + i] = base[i];
    }
    if (tid == 0) offsets[bc * (C_ + 1) + C_] = N_;
    for (int n = tid; n < N_ / 4; n += 1024) {
        int4 c4 = g4[n];
        int n0 = n * 4;
        sidx[bc * N_ + base[c4.x] + atomicAdd(&cur[c4.x], 1)] = n0;
        sidx[bc * N_ + base[c4.y] + atomicAdd(&cur[c4.y], 1)] = n0 + 1;
        sidx[bc * N_ + base[c4.z] + atomicAdd(&cur[c4.z], 1)] = n0 + 2;
        sidx[bc * N_ + base[c4.w] + atomicAdd(&cur[c4.w], 1)] = n0 + 3;
    }
}

// ---------------------------------------------------------------- fused segment sums
// One wave per (b, cluster); Q, K, V together: 12 independent 1KB row-gathers
// in flight per iteration. Index loads for iteration i+1 issued before
// iteration i's data is consumed. Centers written once, pre-scaled by 1/count.
__global__ __launch_bounds__(256) void k_segsum4(const float* __restrict__ q,
                                                 const float* __restrict__ k,
                                                 const float* __restrict__ v,
                                                 const int* __restrict__ offsets,
                                                 const int* __restrict__ sidx,
                                                 float* __restrict__ sums) {
    int bid = blockIdx.x;
    int cg = bid % CG_;
    int b = bid / CG_;
    int wave = threadIdx.x >> 6, lane = threadIdx.x & 63;
    int c = cg * 4 + wave;
    if (c >= C_) return;
    int bc = b & 3;
    int start = offsets[bc * (C_ + 1) + c];
    int end = offsets[bc * (C_ + 1) + c + 1];
    int cnt = end - start;
    int sub = lane >> 4, d4 = lane & 15;

    const float4* q4 = (const float4*)(q + (size_t)b * N_ * D_);
    const float4* k4 = (const float4*)(k + (size_t)b * N_ * D_);
    const float4* v4 = (const float4*)(v + (size_t)b * N_ * D_);
    const int* si = sidx + bc * N_;

    float4 aq = make_float4(0.f, 0.f, 0.f, 0.f);
    float4 ak = make_float4(0.f, 0.f, 0.f, 0.f);
    float4 av = make_float4(0.f, 0.f, 0.f, 0.f);

    if (cnt > 0) {
        int last = end - 1;
        int ia = start + sub, ib = ia + 4, ic = ia + 8, id = ia + 12;
        int ra = si[min(ia, last)], rb = si[min(ib, last)];
        int rc = si[min(ic, last)], rd = si[min(id, last)];
        for (int i0 = start; i0 < end; i0 += 16) {
            int ca = ia, cb = ib, cc = ic, cd = id;
            int ua = ra, ub = rb, uc = rc, ud = rd;
            ia += 16; ib += 16; ic += 16; id += 16;
            if (i0 + 16 < end) {
                ra = si[min(ia, last)]; rb = si[min(ib, last)];
                rc = si[min(ic, last)]; rd = si[min(id, last)];
            }
            float ma = (ca < end) ? 1.f : 0.f;
            float mb = (cb < end) ? 1.f : 0.f;
            float mc = (cc < end) ? 1.f : 0.f;
            float md = (cd < end) ? 1.f : 0.f;
            float4 qa = q4[ua * 16 + d4], qb = q4[ub * 16 + d4];
            float4 qc = q4[uc * 16 + d4], qd = q4[ud * 16 + d4];
            float4 ka = k4[ua * 16 + d4], kb = k4[ub * 16 + d4];
            float4 kc = k4[uc * 16 + d4], kd = k4[ud * 16 + d4];
            float4 va = v4[ua * 16 + d4], vb = v4[ub * 16 + d4];
            float4 vc = v4[uc * 16 + d4], vd = v4[ud * 16 + d4];
            aq.x += ma * qa.x + mb * qb.x + mc * qc.x + md * qd.x;
            aq.y += ma * qa.y + mb * qb.y + mc * qc.y + md * qd.y;
            aq.z += ma * qa.z + mb * qb.z + mc * qc.z + md * qd.z;
            aq.w += ma * qa.w + mb * qb.w + mc * qc.w + md * qd.w;
            ak.x += ma * ka.x + mb * kb.x + mc * kc.x + md * kd.x;
            ak.y += ma * ka.y + mb * kb.y + mc * kc.y + md * kd.y;
            ak.z += ma * ka.z + mb * kb.z + mc * kc.z + md * kd.z;
            ak.w += ma * ka.w + mb * kb.w + mc * kc.w + md * kd.w;
            av.x += ma * va.x + mb * vb.x + mc * vc.x + md * vd.x;
            av.y += ma * va.y + mb * vb.y + mc * vc.y + md * vd.y;
            av.z += ma * va.z + mb * vb.z + mc * vc.z + md * vd.z;
            av.w += ma * va.w + mb * vb.w + mc * vc.w + md * vd.w;
        }
    }
#pragma unroll
    for (int off = 16; off <= 32; off <<= 1) {
        aq.x += __shfl_xor(aq.x, off, 64); aq.y += __shfl_xor(aq.y, off, 64);
        aq.z += __shfl_xor(aq.z, off, 64); aq.w += __shfl_xor(aq.w, off, 64);
        ak.x += __shfl_xor(ak.x, off, 64); ak.y += __shfl_xor(ak.y, off, 64);
        ak.z += __shfl_xor(ak.z, off, 64); ak.w += __shfl_xor(ak.w, off, 64);
        av.x += __shfl_xor(av.x, off, 64); av.y += __shfl_xor(av.y, off, 64);
        av.z += __shfl_xor(av.z, off, 64); av.w += __shfl_xor(av.w, off, 64);
    }
    if (sub == 0) {
        float w = (cnt > 0) ? 1.f / (float)cnt : 0.f;
        float4 oq = make_float4(aq.x * w, aq.y * w, aq.z * w, aq.w * w);
        float4 ok = make_float4(ak.x * w, ak.y * w, ak.z * w, ak.w * w);
        float4 ov = make_float4(av.x * w, av.y * w, av.z * w, av.w * w);
        ((float4*)(sums + (size_t)b * C_ * D_))[c * 16 + d4] = oq;
        ((float4*)(sums + ((size_t)B_ + b) * C_ * D_))[c * 16 + d4] = ok;
        ((float4*)(sums + ((size_t)2 * B_ + b) * C_ * D_))[c * 16 + d4] = ov;
    }
}

// ---------------------------------------------------------------- attention over centers
// grid: B * 8 blocks (17 q-rows per block -> exactly 256 blocks, one scheduling
// round). K and V centers in LDS (the PV path MUST be LDS — round-1 showed the
// global-V variant is L2-latency-bound at 59 µs). Q-row reads in the QK loop
// are wave-uniform broadcasts -> read straight from global (L2-hit, one
// cacheline per load); dropping the qr4 staging buffer puts LDS at 79.1 KB,
// just under the 80 KB threshold for 2 blocks/CU. __launch_bounds__(256,2)
// pins VGPR <= 256 so occupancy is LDS-limited, not VGPR-limited.
__global__ __launch_bounds__(256, 2) void k_attn(const float* __restrict__ sums,
                                                 const float* __restrict__ counts,
                                                 float* __restrict__ vout,
                                                 float* __restrict__ aout) {
    __shared__ float4 kc4[C_ * 17];       // K centers, 16 data float4 + 1 pad
    __shared__ float4 vc4[C_ * 17];       // V centers
    __shared__ float cnt_s[C_];
    __shared__ float arow[4][4][132];     // per-wave A rows (k=0..128, pad to 132)

    int b = blockIdx.x >> 3;
    int qg = blockIdx.x & 7;
    int q0 = qg * QROWS_;
    int qcnt = min(QROWS_, C_ - q0);
    int tid = threadIdx.x;

    for (int i = tid; i < C_; i += 256)
        cnt_s[i] = counts[(b & 3) * C_ + i];

    const float4* qsum4 = (const float4*)(sums + (size_t)b * C_ * D_);
    const float4* ksum4 = (const float4*)(sums + ((size_t)B_ + b) * C_ * D_);
    const float4* vsum4 = (const float4*)(sums + ((size_t)2 * B_ + b) * C_ * D_);

    for (int i = tid; i < C_ * 16; i += 256) {
        int c = i >> 4, d4 = i & 15;
        kc4[c * 17 + d4] = ksum4[i];
        vc4[c * 17 + d4] = vsum4[i];
    }
    __syncthreads();

    int wave = __builtin_amdgcn_readfirstlane(tid >> 6);
    int lane = tid & 63;

    for (int tt = wave; tt * 4 < qcnt; tt += 4) {
        int t4 = tt * 4;
        // per-tile Q row pointers (wave-uniform; clamped for the tail)
        const float4* qp0 = qsum4 + (size_t)(q0 + min(t4 + 0, qcnt - 1)) * 16;
        const float4* qp1 = qsum4 + (size_t)(q0 + min(t4 + 1, qcnt - 1)) * 16;
        const float4* qp2 = qsum4 + (size_t)(q0 + min(t4 + 2, qcnt - 1)) * 16;
        const float4* qp3 = qsum4 + (size_t)(q0 + min(t4 + 3, qcnt - 1)) * 16;
        // ---- QK: 4 q-rows x (k=lane, k=lane+64, k=128)
        float s0[4] = {0, 0, 0, 0}, s1[4] = {0, 0, 0, 0}, s2[4] = {0, 0, 0, 0};
#pragma unroll 4
        for (int d4 = 0; d4 < 16; d4++) {
            float4 kv0 = kc4[lane * 17 + d4];
            float4 kv1 = kc4[(lane + 64) * 17 + d4];
            float4 kv2 = kc4[128 * 17 + d4];
            float4 qv0 = qp0[d4], qv1 = qp1[d4], qv2 = qp2[d4], qv3 = qp3[d4];
            s0[0] += qv0.x * kv0.x + qv0.y * kv0.y + qv0.z * kv0.z + qv0.w * kv0.w;
            s1[0] += qv0.x * kv1.x + qv0.y * kv1.y + qv0.z * kv1.z + qv0.w * kv1.w;
            s2[0] += qv0.x * kv2.x + qv0.y * kv2.y + qv0.z * kv2.z + qv0.w * kv2.w;
            s0[1] += qv1.x * kv0.x + qv1.y * kv0.y + qv1.z * kv0.z + qv1.w * kv0.w;
            s1[1] += qv1.x * kv1.x + qv1.y * kv1.y + qv1.z * kv1.z + qv1.w * kv1.w;
            s2[1] += qv1.x * kv2.x + qv1.y * kv2.y + qv1.z * kv2.z + qv1.w * kv2.w;
            s0[2] += qv2.x * kv0.x + qv2.y * kv0.y + qv2.z * kv0.z + qv2.w * kv0.w;
            s1[2] += qv2.x * kv1.x + qv2.y * kv1.y + qv2.z * kv1.z + qv2.w * kv1.w;
            s2[2] += qv2.x * kv2.x + qv2.y * kv2.y + qv2.z * kv2.z + qv2.w * kv2.w;
            s0[3] += qv3.x * kv0.x + qv3.y * kv0.y + qv3.z * kv0.z + qv3.w * kv0.w;
            s1[3] += qv3.x * kv1.x + qv3.y * kv1.y + qv3.z * kv1.z + qv3.w * kv1.w;
            s2[3] += qv3.x * kv2.x + qv3.y * kv2.y + qv3.z * kv2.z + qv3.w * kv2.w;
        }
        // ---- softmax (weighted by counts, renormalized)
#pragma unroll
        for (int r = 0; r < 4; r++) {
            if (t4 + r >= qcnt) break;
            int qrow = q0 + t4 + r;
            float m = fmaxf(s0[r], s1[r]);
            if (lane == 0) m = fmaxf(m, s2[r]);
            for (int off = 32; off > 0; off >>= 1)
                m = fmaxf(m, __shfl_xor(m, off, 64));
            float e0 = __expf(s0[r] - m) * cnt_s[lane];
            float e1 = __expf(s1[r] - m) * cnt_s[lane + 64];
            float e2 = (lane == 0) ? __expf(s2[r] - m) * cnt_s[128] : 0.f;
            float sum = e0 + e1 + e2;
            for (int off = 32; off > 0; off >>= 1)
                sum += __shfl_xor(sum, off, 64);
            float inv = 1.f / sum;
            float a0 = e0 * inv, a1 = e1 * inv;
            arow[wave][r][lane] = a0;
            arow[wave][r][64 + lane] = a1;
            if (lane == 0) {
                arow[wave][r][128] = e2 * inv;
                aout[b * C_ + qrow] = a0;   // A_full[:, :, 0]
            }
        }
        __builtin_amdgcn_s_waitcnt(0);       // arow writes visible in-wave
        __builtin_amdgcn_sched_barrier(0);   // don't let ds_reads hoist above
        // ---- V product: lane = (row within tile, d4)
        int rr = lane >> 4, d4 = lane & 15;
        const float4* ar4 = (const float4*)arow[wave][rr];
        float4 o = make_float4(0.f, 0.f, 0.f, 0.f);
        for (int k4 = 0; k4 < 32; k4++) {
            float4 a4 = ar4[k4];
            float4 v0 = vc4[(k4 * 4 + 0) * 17 + d4];
            float4 v1 = vc4[(k4 * 4 + 1) * 17 + d4];
            float4 v2 = vc4[(k4 * 4 + 2) * 17 + d4];
            float4 v3 = vc4[(k4 * 4 + 3) * 17 + d4];
            o.x += a4.x * v0.x + a4.y * v1.x + a4.z * v2.x + a4.w * v3.x;
            o.y += a4.x * v0.y + a4.y * v1.y + a4.z * v2.y + a4.w * v3.y;
            o.z += a4.x * v0.z + a4.y * v1.z + a4.z * v2.z + a4.w * v3.z;
            o.w += a4.x * v0.w + a4.y * v1.w + a4.z * v2.w + a4.w * v3.w;
        }
        {
            float a128 = arow[wave][rr][128];
            float4 vv = vc4[128 * 17 + d4];
            o.x += a128 * vv.x; o.y += a128 * vv.y;
            o.z += a128 * vv.z; o.w += a128 * vv.w;
        }
        if (t4 + rr < qcnt) {
            float4* dst = (float4*)(vout + ((size_t)b * C_ + (q0 + t4 + rr)) * D_);
            dst[d4] = o;
        }
    }
}

// ---------------------------------------------------------------- gather
__global__ __launch_bounds__(256) void k_gather(const float* __restrict__ vout,
                                                const int* __restrict__ cl,
                                                float* __restrict__ out) {
    int idx = blockIdx.x * 256 + threadIdx.x;   // over B*N*16 float4s
    int d4 = idx & 15;
    int n = (idx >> 4) & (N_ - 1);
    int b = idx >> 16;
    int c = cl[(b & 3) * N_ + n];
    const float4* src = (const float4*)(vout + ((size_t)b * C_ + c) * D_);
    ((float4*)out)[idx] = src[d4];
}

// ---------------------------------------------------------------- launch
extern "C" void kernel_launch(void* const* d_in, const int* in_sizes, int n_in,
                              void* d_out, int out_size, void* d_ws, size_t ws_size,
                              hipStream_t stream) {
    const float* q = (const float*)d_in[0];
    const float* k = (const float*)d_in[1];
    const float* v = (const float*)d_in[2];
    const int* cl = (const int*)d_in[3];
    float* out = (float*)d_out;
    float* aout = out + (size_t)B_ * N_ * D_;   // A_full[:, :, 0] tail

    float* ws = (float*)d_ws;
    float* counts = ws;                                   // [4][C_] (pad to 1024)
    float* sums = ws + 1024;                              // [3][B_][C_][D_] pre-scaled centers
    float* vout = sums + (size_t)3 * B_ * C_ * D_;        // [B_][C_][D_]
    int* offsets = (int*)(vout + (size_t)B_ * C_ * D_);   // [4][C_+1]
    int* sidx = offsets + 4 * (C_ + 1);                   // [4][N_]

    k_sort<<<BC_, 1024, 0, stream>>>(cl, counts, offsets, sidx);
    k_segsum4<<<B_ * CG_, 256, 0, stream>>>(q, k, v, offsets, sidx, sums);
    k_attn<<<B_ * 8, 256, 0, stream>>>(sums, counts, vout, aout);
    k_gather<<<(B_ * N_ * 16) / 256, 256, 0, stream>>>(vout, cl, out);
}